// Round 13
// baseline (274.914 us; speedup 1.0000x reference)
//
#include <hip/hip_runtime.h>
#include <hip/hip_bf16.h>

// LocalKNN: B=64, Way=5, D=64, Nq=1024, Ns=1024, K=3.
// Round 13: ABLATION round. r12 path kept intact (correct output, ~99us).
// Two diagnostic kernels appended, writing only to ws scratch:
//   abl_loads: staging loop only (gload_lds+vmcnt+barrier), x8 sweeps
//   abl_ins:   loads + ds_read + INS stream (no MFMA),      x2 sweeps
// rocprof top-5 shows the slowest component's per-dispatch time; total dur_us
// minus 99 gives the sum of the rest. Decision tree in the journal.

using bf16x8 = __attribute__((ext_vector_type(8))) short;  // 8 bf16 = 4 VGPRs
using f32x4  = __attribute__((ext_vector_type(4))) float;

__device__ inline unsigned cvt_pk_bf16(float lo, float hi) {
    unsigned r;
    asm("v_cvt_pk_bf16_f32 %0, %1, %2" : "=v"(r) : "v"(lo), "v"(hi));
    return r;
}

__device__ inline uint4 pack8cvt(const float* v) {
    uint4 r;
    r.x = cvt_pk_bf16(v[0], v[1]);
    r.y = cvt_pk_bf16(v[2], v[3]);
    r.z = cvt_pk_bf16(v[4], v[5]);
    r.w = cvt_pk_bf16(v[6], v[7]);
    return r;
}

// branchless insert of v into sorted top-3 (t0>=t1>=t2): 1 max + 2 med3
#define INS(v, T0, T1, T2) do {                         \
    float _v = (v);                                     \
    float _n0 = fmaxf((T0), _v);                        \
    float _n1 = __builtin_amdgcn_fmed3f(_v, (T0), (T1));\
    float _n2 = __builtin_amdgcn_fmed3f(_v, (T1), (T2));\
    (T0) = _n0; (T1) = _n1; (T2) = _n2;                 \
} while (0)

// async 16B/lane global->LDS (LDS dest = wave-uniform base + lane*16)
__device__ inline void gload16(const void* g, void* lds) {
    __builtin_amdgcn_global_load_lds(
        (const __attribute__((address_space(1))) unsigned int*)g,
        (__attribute__((address_space(3))) unsigned int*)lds,
        16, 0, 0);
}

// ============================= fast path =====================================
// Fragment layout: per 16-col tile, 128 uint4 slots; slot h*16 + r holds
// column (tile*16+r)'s elements d = 8h..8h+7 as 4 packed bf16-pairs.

// ---- prep_all: raw Q/S -> bf16 fragments (+ rnq) ----------------------------
__global__ __launch_bounds__(256) void prep_all(const float* __restrict__ Q,
                                                const float* __restrict__ S,
                                                uint4* __restrict__ Qbf,
                                                uint4* __restrict__ Sbf,
                                                float* __restrict__ rnq) {
    const int blk = blockIdx.x;
    if (blk < 256) {
        const int b = blk >> 2;
        const int col = ((blk & 3) << 8) + threadIdx.x;      // q in 0..1023
        const float* p = Q + (size_t)b * 65536 + col;
        float v[64];
        #pragma unroll
        for (int d = 0; d < 64; ++d) v[d] = p[(size_t)d << 10];
        float ss = 0.f;
        #pragma unroll
        for (int d = 0; d < 64; ++d) ss += v[d] * v[d];
        rnq[(b << 10) + col] = 1.0f / fmaxf(sqrtf(ss), 1e-12f);
        uint4* ob = Qbf + ((size_t)(b << 6) + (col >> 4)) * 128 + (col & 15);
        #pragma unroll
        for (int h = 0; h < 8; ++h)
            ob[h << 4] = pack8cvt(&v[h << 3]);
    } else {
        const int bw = (blk - 256) >> 2;
        const int col = ((blk & 3) << 8) + threadIdx.x;      // s in 0..1023
        const float* p = S + (size_t)bw * 65536 + col;
        float v[64];
        #pragma unroll
        for (int d = 0; d < 64; ++d) v[d] = p[(size_t)d << 10];
        float ss = 0.f;
        #pragma unroll
        for (int d = 0; d < 64; ++d) ss += v[d] * v[d];
        const float rs = 1.0f / fmaxf(sqrtf(ss), 1e-12f);
        #pragma unroll
        for (int d = 0; d < 64; ++d) v[d] *= rs;
        uint4* ob = Sbf + ((size_t)(bw << 6) + (col >> 4)) * 128 + (col & 15);
        #pragma unroll
        for (int h = 0; h < 8; ++h)
            ob[h << 4] = pack8cvt(&v[h << 3]);
    }
}

// one 16-s tile: 2 ds_reads, 4 MFMA, 8 INS (2 q-tiles)
__device__ __forceinline__ void compute_tile(const uint4* sp, int lane,
                                             const bf16x8 (&bq)[2][2],
                                             float (&t0)[2], float (&t1)[2],
                                             float (&t2)[2]) {
    bf16x8 a0 = *reinterpret_cast<const bf16x8*>(&sp[lane]);
    bf16x8 a1 = *reinterpret_cast<const bf16x8*>(&sp[64 + lane]);
    const f32x4 z = {0.f, 0.f, 0.f, 0.f};
    __builtin_amdgcn_s_setprio(1);
    f32x4 c0 = __builtin_amdgcn_mfma_f32_16x16x32_bf16(a0, bq[0][0], z, 0, 0, 0);
    c0 = __builtin_amdgcn_mfma_f32_16x16x32_bf16(a1, bq[0][1], c0, 0, 0, 0);
    f32x4 c1 = __builtin_amdgcn_mfma_f32_16x16x32_bf16(a0, bq[1][0], z, 0, 0, 0);
    c1 = __builtin_amdgcn_mfma_f32_16x16x32_bf16(a1, bq[1][1], c1, 0, 0, 0);
    __builtin_amdgcn_s_setprio(0);
    INS(c0[0], t0[0], t1[0], t2[0]);
    INS(c0[1], t0[0], t1[0], t2[0]);
    INS(c0[2], t0[0], t1[0], t2[0]);
    INS(c0[3], t0[0], t1[0], t2[0]);
    INS(c1[0], t0[1], t1[1], t2[1]);
    INS(c1[1], t0[1], t1[1], t2[1]);
    INS(c1[2], t0[1], t1[1], t2[1]);
    INS(c1[3], t0[1], t1[1], t2[1]);
}

// ---- main: r12 structure, unchanged -----------------------------------------
__global__ __launch_bounds__(256, 8) void knn_main(const uint4* __restrict__ Qbf,
                                                   const uint4* __restrict__ Sbf,
                                                   const float* __restrict__ rnq,
                                                   float* __restrict__ partial) {
    __shared__ uint4 ring[5 * 256];     // 5 pair-slots x 4 KB = 20 KB
    __shared__ float wsum[4];
    const int lin = blockIdx.x;
    const int l   = (lin & 7) * 320 + (lin >> 3);   // 2560 = 8*320, bijective
    const int qc  = l & 7;
    const int bw  = l >> 3;                          // b*5 + w
    const int b   = bw / 5;
    const int wv = threadIdx.x >> 6, lane = threadIdx.x & 63;
    const int sp0 = qc << 2;                         // staggered start pair

    const uint4* qb = Qbf + ((size_t)(b << 6) + (qc << 3) + (wv << 1)) * 128 + lane;
    bf16x8 bq[2][2];
    #pragma unroll
    for (int qt = 0; qt < 2; ++qt)
        #pragma unroll
        for (int c = 0; c < 2; ++c)
            bq[qt][c] = *reinterpret_cast<const bf16x8*>(&qb[qt * 128 + (c << 6)]);

    const char* sbase = (const char*)(Sbf + (size_t)(bw << 6) * 128);
    const size_t toff = (size_t)threadIdx.x * 16;

    float t0[2], t1[2], t2[2];
    #pragma unroll
    for (int qt = 0; qt < 2; ++qt) { t0[qt] = -1e30f; t1[qt] = -1e30f; t2[qt] = -1e30f; }

    #pragma unroll
    for (int p = 0; p < 3; ++p)
        gload16(sbase + (size_t)((p + sp0) & 31) * 4096 + toff,
                &ring[(p << 8) + (wv << 6)]);

    int rslot = 0, wslot = 3;
    for (int p = 0; p <= 28; ++p) {
        gload16(sbase + (size_t)((p + 3 + sp0) & 31) * 4096 + toff,
                &ring[(wslot << 8) + (wv << 6)]);
        asm volatile("s_waitcnt vmcnt(3)" ::: "memory");
        __builtin_amdgcn_s_barrier();
        const uint4* sp = &ring[rslot << 8];
        compute_tile(sp, lane, bq, t0, t1, t2);
        compute_tile(sp + 128, lane, bq, t0, t1, t2);
        if (++rslot == 5) rslot = 0;
        if (++wslot == 5) wslot = 0;
    }
    asm volatile("s_waitcnt vmcnt(0)" ::: "memory");
    __builtin_amdgcn_s_barrier();
    {
        const uint4* sp = &ring[4 << 8];
        compute_tile(sp, lane, bq, t0, t1, t2);
        compute_tile(sp + 128, lane, bq, t0, t1, t2);
        sp = &ring[0];
        compute_tile(sp, lane, bq, t0, t1, t2);
        compute_tile(sp + 128, lane, bq, t0, t1, t2);
        sp = &ring[1 << 8];
        compute_tile(sp, lane, bq, t0, t1, t2);
        compute_tile(sp + 128, lane, bq, t0, t1, t2);
    }

    float s3 = 0.f;
    #pragma unroll
    for (int qt = 0; qt < 2; ++qt) {
        #pragma unroll
        for (int m = 16; m <= 32; m <<= 1) {
            float b0 = __shfl_xor(t0[qt], m);
            float b1 = __shfl_xor(t1[qt], m);
            float b2 = __shfl_xor(t2[qt], m);
            INS(b0, t0[qt], t1[qt], t2[qt]);
            INS(b1, t0[qt], t1[qt], t2[qt]);
            INS(b2, t0[qt], t1[qt], t2[qt]);
        }
        const int qg = (qc << 7) + (wv << 5) + (qt << 4) + (lane & 15);
        s3 += (t0[qt] + t1[qt] + t2[qt]) * rnq[(b << 10) + qg];
    }
    #pragma unroll
    for (int m = 1; m < 64; m <<= 1) s3 += __shfl_xor(s3, m);
    s3 *= 0.25f;
    if (lane == 0) wsum[wv] = s3;
    __syncthreads();
    if (threadIdx.x == 0)
        partial[((size_t)bw << 3) + qc] = (wsum[0] + wsum[1]) + (wsum[2] + wsum[3]);
}

__global__ void finalize8(const float* __restrict__ partial, float* __restrict__ out) {
    int i = blockIdx.x * blockDim.x + threadIdx.x;
    if (i < 320) {
        float a = 0.f;
        #pragma unroll
        for (int k = 0; k < 8; ++k) a += partial[8 * i + k];
        out[i] = a;
    }
}

// ============================ ablation kernels ===============================
// abl_loads: the staging loop ONLY (gload_lds + vmcnt(3) + barrier), x8 sweeps.
__global__ __launch_bounds__(256, 8) void abl_loads(const uint4* __restrict__ Sbf,
                                                    float* __restrict__ dump) {
    __shared__ uint4 ring[5 * 256];
    const int lin = blockIdx.x;
    const int l   = (lin & 7) * 320 + (lin >> 3);
    const int qc  = l & 7;
    const int bw  = l >> 3;
    const int wv = threadIdx.x >> 6;
    const int sp0 = qc << 2;
    const char* sbase = (const char*)(Sbf + (size_t)(bw << 6) * 128);
    const size_t toff = (size_t)threadIdx.x * 16;

    for (int r = 0; r < 8; ++r) {
        #pragma unroll
        for (int p = 0; p < 3; ++p)
            gload16(sbase + (size_t)((p + sp0) & 31) * 4096 + toff,
                    &ring[(p << 8) + (wv << 6)]);
        int wslot = 3;
        for (int p = 0; p <= 28; ++p) {
            gload16(sbase + (size_t)((p + 3 + sp0) & 31) * 4096 + toff,
                    &ring[(wslot << 8) + (wv << 6)]);
            asm volatile("s_waitcnt vmcnt(3)" ::: "memory");
            __builtin_amdgcn_s_barrier();
            if (++wslot == 5) wslot = 0;
        }
        asm volatile("s_waitcnt vmcnt(0)" ::: "memory");
        __builtin_amdgcn_s_barrier();
    }
    float v = ((const float*)ring)[threadIdx.x];
    asm volatile("" :: "v"(v));                 // keep the read
    if (threadIdx.x == 0) dump[blockIdx.x] = v;
}

// abl_ins: loads + ds_read + INS stream (no MFMA; raw LDS bits as floats), x2.
__device__ __forceinline__ void ins_raw_tile(const uint4* sp, int lane,
                                             float (&t0)[2], float (&t1)[2],
                                             float (&t2)[2]) {
    f32x4 c0 = *reinterpret_cast<const f32x4*>(&sp[lane]);
    f32x4 c1 = *reinterpret_cast<const f32x4*>(&sp[64 + lane]);
    INS(c0[0], t0[0], t1[0], t2[0]);
    INS(c0[1], t0[0], t1[0], t2[0]);
    INS(c0[2], t0[0], t1[0], t2[0]);
    INS(c0[3], t0[0], t1[0], t2[0]);
    INS(c1[0], t0[1], t1[1], t2[1]);
    INS(c1[1], t0[1], t1[1], t2[1]);
    INS(c1[2], t0[1], t1[1], t2[1]);
    INS(c1[3], t0[1], t1[1], t2[1]);
}

__global__ __launch_bounds__(256, 8) void abl_ins(const uint4* __restrict__ Sbf,
                                                  float* __restrict__ dump) {
    __shared__ uint4 ring[5 * 256];
    const int lin = blockIdx.x;
    const int l   = (lin & 7) * 320 + (lin >> 3);
    const int qc  = l & 7;
    const int bw  = l >> 3;
    const int wv = threadIdx.x >> 6, lane = threadIdx.x & 63;
    const int sp0 = qc << 2;
    const char* sbase = (const char*)(Sbf + (size_t)(bw << 6) * 128);
    const size_t toff = (size_t)threadIdx.x * 16;

    float t0[2], t1[2], t2[2];
    #pragma unroll
    for (int qt = 0; qt < 2; ++qt) { t0[qt] = -1e30f; t1[qt] = -1e30f; t2[qt] = -1e30f; }

    for (int r = 0; r < 2; ++r) {
        #pragma unroll
        for (int p = 0; p < 3; ++p)
            gload16(sbase + (size_t)((p + sp0) & 31) * 4096 + toff,
                    &ring[(p << 8) + (wv << 6)]);
        int rslot = 0, wslot = 3;
        for (int p = 0; p <= 28; ++p) {
            gload16(sbase + (size_t)((p + 3 + sp0) & 31) * 4096 + toff,
                    &ring[(wslot << 8) + (wv << 6)]);
            asm volatile("s_waitcnt vmcnt(3)" ::: "memory");
            __builtin_amdgcn_s_barrier();
            const uint4* sp = &ring[rslot << 8];
            ins_raw_tile(sp, lane, t0, t1, t2);
            ins_raw_tile(sp + 128, lane, t0, t1, t2);
            if (++rslot == 5) rslot = 0;
            if (++wslot == 5) wslot = 0;
        }
        asm volatile("s_waitcnt vmcnt(0)" ::: "memory");
        __builtin_amdgcn_s_barrier();
        {
            const uint4* sp = &ring[4 << 8];
            ins_raw_tile(sp, lane, t0, t1, t2);
            ins_raw_tile(sp + 128, lane, t0, t1, t2);
            sp = &ring[0];
            ins_raw_tile(sp, lane, t0, t1, t2);
            ins_raw_tile(sp + 128, lane, t0, t1, t2);
            sp = &ring[1 << 8];
            ins_raw_tile(sp, lane, t0, t1, t2);
            ins_raw_tile(sp + 128, lane, t0, t1, t2);
        }
    }
    float s = t0[0] + t1[0] + t2[0] + t0[1] + t1[1] + t2[1];
    if (threadIdx.x == 0) dump[blockIdx.x] = s;
}

// ============================ fallback path (round-2) ========================
__global__ void norms_kernel(const float* __restrict__ Q, const float* __restrict__ S,
                             float* __restrict__ rnq, float* __restrict__ rns) {
    int gid = blockIdx.x * blockDim.x + threadIdx.x;
    if (gid < 65536) {
        int b = gid >> 10, qi = gid & 1023;
        const float* p = Q + (size_t)b * 65536 + qi;
        float ss = 0.f;
        #pragma unroll
        for (int d = 0; d < 64; ++d) { float v = p[(size_t)d * 1024]; ss += v * v; }
        rnq[gid] = 1.0f / fmaxf(sqrtf(ss), 1e-12f);
    } else {
        int v = gid - 65536;
        int bw = v >> 10, si = v & 1023;
        const float* p = S + (size_t)bw * 65536 + si;
        float ss = 0.f;
        #pragma unroll
        for (int d = 0; d < 64; ++d) { float x = p[(size_t)d * 1024]; ss += x * x; }
        rns[v] = 1.0f / fmaxf(sqrtf(ss), 1e-12f);
    }
}

__global__ __launch_bounds__(512, 4) void knn_fb(
        const float* __restrict__ Q, const float* __restrict__ S,
        const float* __restrict__ rnq, const float* __restrict__ rns,
        float* __restrict__ partial) {
    __shared__ uint4 qfrag[16 * 128];
    __shared__ uint4 sfrag[2][4 * 128];
    __shared__ float wsum[8];

    const int qc = blockIdx.x, w = blockIdx.y, b = blockIdx.z;
    const int t = threadIdx.x, wv = t >> 6, lane = t & 63;

    const float* Qb   = Q + (size_t)b * 65536;
    const float* Sb   = S + (size_t)(b * 5 + w) * 65536;
    const float* rnqb = rnq + (b << 10);
    const float* rnsb = rns + ((b * 5 + w) << 10);

    bf16x8 bq[4][2];
    for (int ph = 0; ph < 2; ++ph) {
        for (int sub = 0; sub < 4; ++sub) {
            int qg = (qc << 9) + (ph << 8) + (sub << 6) + lane;
            float v[8];
            #pragma unroll
            for (int i = 0; i < 8; ++i)
                v[i] = Qb[(size_t)((wv << 3) + i) * 1024 + qg];
            qfrag[((sub << 2) + (lane >> 4)) * 128 + (wv << 4) + (lane & 15)] = pack8cvt(v);
        }
        __syncthreads();
        if ((wv >> 2) == ph) {
            #pragma unroll
            for (int qt = 0; qt < 4; ++qt)
                #pragma unroll
                for (int c = 0; c < 2; ++c)
                    bq[qt][c] = *reinterpret_cast<const bf16x8*>(
                        &qfrag[(((wv & 3) << 2) + qt) * 128 + (c << 6) + lane]);
        }
        __syncthreads();
    }

    {
        float sv[8]; float rs = rnsb[lane];
        #pragma unroll
        for (int i = 0; i < 8; ++i)
            sv[i] = Sb[(size_t)((wv << 3) + i) * 1024 + lane] * rs;
        sfrag[0][(lane >> 4) * 128 + (wv << 4) + (lane & 15)] = pack8cvt(sv);
    }
    __syncthreads();

    float t0[4], t1[4], t2[4];
    #pragma unroll
    for (int qt = 0; qt < 4; ++qt) { t0[qt] = -1e30f; t1[qt] = -1e30f; t2[qt] = -1e30f; }
    int cur = 0;
    const float* sp = Sb + ((wv << 3) << 10) + lane;

    for (int blk = 0; blk < 16; ++blk) {
        float sv[8]; float rs;
        if (blk < 15) {
            const int sb_ = (blk + 1) << 6;
            rs = rnsb[sb_ + lane];
            #pragma unroll
            for (int i = 0; i < 8; ++i)
                sv[i] = sp[(size_t)(i << 10) + sb_];
        }
        #pragma unroll
        for (int st = 0; st < 4; ++st) {
            bf16x8 a0 = *reinterpret_cast<const bf16x8*>(&sfrag[cur][st * 128 + lane]);
            bf16x8 a1 = *reinterpret_cast<const bf16x8*>(&sfrag[cur][st * 128 + 64 + lane]);
            #pragma unroll
            for (int qt = 0; qt < 4; ++qt) {
                f32x4 c = {0.f, 0.f, 0.f, 0.f};
                c = __builtin_amdgcn_mfma_f32_16x16x32_bf16(a0, bq[qt][0], c, 0, 0, 0);
                c = __builtin_amdgcn_mfma_f32_16x16x32_bf16(a1, bq[qt][1], c, 0, 0, 0);
                #pragma unroll
                for (int j = 0; j < 4; ++j)
                    INS(c[j], t0[qt], t1[qt], t2[qt]);
            }
        }
        if (blk < 15) {
            #pragma unroll
            for (int i = 0; i < 8; ++i) sv[i] *= rs;
            sfrag[cur ^ 1][(lane >> 4) * 128 + (wv << 4) + (lane & 15)] = pack8cvt(sv);
        }
        __syncthreads();
        cur ^= 1;
    }

    float s3 = 0.f;
    #pragma unroll
    for (int qt = 0; qt < 4; ++qt) {
        #pragma unroll
        for (int m = 16; m <= 32; m <<= 1) {
            float b0 = __shfl_xor(t0[qt], m);
            float b1 = __shfl_xor(t1[qt], m);
            float b2 = __shfl_xor(t2[qt], m);
            INS(b0, t0[qt], t1[qt], t2[qt]);
            INS(b1, t0[qt], t1[qt], t2[qt]);
            INS(b2, t0[qt], t1[qt], t2[qt]);
        }
        int qg = (qc << 9) + (wv << 6) + (qt << 4) + (lane & 15);
        s3 += (t0[qt] + t1[qt] + t2[qt]) * rnqb[qg];
    }
    #pragma unroll
    for (int m = 1; m < 64; m <<= 1) s3 += __shfl_xor(s3, m);
    s3 *= 0.25f;
    if (lane == 0) wsum[wv] = s3;
    __syncthreads();
    if (t == 0) {
        float acc = 0.f;
        #pragma unroll
        for (int i = 0; i < 8; ++i) acc += wsum[i];
        partial[((b * 5 + w) << 1) + qc] = acc;
    }
}

__global__ void finalize2(const float* __restrict__ partial, float* __restrict__ out) {
    int i = blockIdx.x * blockDim.x + threadIdx.x;
    if (i < 320)
        out[i] = partial[2 * i] + partial[2 * i + 1];
}

// =============================================================================
extern "C" void kernel_launch(void* const* d_in, const int* in_sizes, int n_in,
                              void* d_out, int out_size, void* d_ws, size_t ws_size,
                              hipStream_t stream) {
    const float* Q = (const float*)d_in[0];   // (64,64,32,32)
    const float* S = (const float*)d_in[1];   // (64,5,64,1024)
    float* out = (float*)d_out;               // (64,5)

    // ws: Qbf 8MB | Sbf 41.9MB | rnq 256KB | partial 10KB | dumpL 10KB | dumpI 10KB
    const size_t QBF = 8388608ull, SBF = 41943040ull, RNQ = 262144ull;
    const size_t PAR = 10240ull, DMP = 10240ull;
    const size_t NEED = QBF + SBF + RNQ + PAR + 2 * DMP;
    if (ws_size >= NEED) {
        char* base = (char*)d_ws;
        uint4* Qbf     = (uint4*)base;
        uint4* Sbf     = (uint4*)(base + QBF);
        float* rnq     = (float*)(base + QBF + SBF);
        float* partial = (float*)(base + QBF + SBF + RNQ);
        float* dumpL   = (float*)(base + QBF + SBF + RNQ + PAR);
        float* dumpI   = (float*)(base + QBF + SBF + RNQ + PAR + DMP);
        prep_all<<<1536, 256, 0, stream>>>(Q, S, Qbf, Sbf, rnq);
        knn_main<<<2560, 256, 0, stream>>>(Qbf, Sbf, rnq, partial);
        finalize8<<<2, 256, 0, stream>>>(partial, out);
        // diagnostics (write only to ws scratch)
        abl_loads<<<2560, 256, 0, stream>>>(Sbf, dumpL);
        abl_ins<<<2560, 256, 0, stream>>>(Sbf, dumpI);
    } else {
        float* rnq = (float*)d_ws;
        float* rns = rnq + 65536;
        float* partial = rns + 327680;
        norms_kernel<<<(65536 + 327680) / 256, 256, 0, stream>>>(Q, S, rnq, rns);
        knn_fb<<<dim3(2, 5, 64), 512, 0, stream>>>(Q, S, rnq, rns, partial);
        finalize2<<<2, 256, 0, stream>>>(partial, out);
    }
}

// Round 14
// 95.422 us; speedup vs baseline: 2.8810x; 2.8810x over previous
//
#include <hip/hip_runtime.h>
#include <hip/hip_bf16.h>

// LocalKNN: B=64, Way=5, D=64, Nq=1024, Ns=1024, K=3.
// out[b,w] = sum_q rnq[q] * sum(top3_s( <q_bq, shat_bws> ))
// Round 14: BARRIER-FREE main loop. r13 ablation: loads sweep 12.4us (L2-BW),
// INS sweep 49us, MFMA adds +26us fully serial -> the block-wide vmcnt+barrier
// phase-locked all waves (no MFMA/VALU cross-wave overlap, synchronized stalls).
// Now: wave = 4 q-tiles x 32 s-tiles (s-half), PRIVATE 5-slot/10KB LDS ring,
// per-wave gload_lds + counted vmcnt(6), zero barriers in the loop. Cross-half
// top-3 merge once at the end via LDS + one __syncthreads.

using bf16x8 = __attribute__((ext_vector_type(8))) short;  // 8 bf16 = 4 VGPRs
using f32x4  = __attribute__((ext_vector_type(4))) float;

__device__ inline unsigned cvt_pk_bf16(float lo, float hi) {
    unsigned r;
    asm("v_cvt_pk_bf16_f32 %0, %1, %2" : "=v"(r) : "v"(lo), "v"(hi));
    return r;
}

__device__ inline uint4 pack8cvt(const float* v) {
    uint4 r;
    r.x = cvt_pk_bf16(v[0], v[1]);
    r.y = cvt_pk_bf16(v[2], v[3]);
    r.z = cvt_pk_bf16(v[4], v[5]);
    r.w = cvt_pk_bf16(v[6], v[7]);
    return r;
}

// branchless insert of v into sorted top-3 (t0>=t1>=t2): 1 max + 2 med3
#define INS(v, T0, T1, T2) do {                         \
    float _v = (v);                                     \
    float _n0 = fmaxf((T0), _v);                        \
    float _n1 = __builtin_amdgcn_fmed3f(_v, (T0), (T1));\
    float _n2 = __builtin_amdgcn_fmed3f(_v, (T1), (T2));\
    (T0) = _n0; (T1) = _n1; (T2) = _n2;                 \
} while (0)

// async 16B/lane global->LDS (LDS dest = wave-uniform base + lane*16)
__device__ inline void gload16(const void* g, void* lds) {
    __builtin_amdgcn_global_load_lds(
        (const __attribute__((address_space(1))) unsigned int*)g,
        (__attribute__((address_space(3))) unsigned int*)lds,
        16, 0, 0);
}

// ============================= fast path =====================================
// Fragment layout: per 16-col tile, 128 uint4 slots; slot h*16 + r holds
// column (tile*16+r)'s elements d = 8h..8h+7 as 4 packed bf16-pairs.

// ---- prep_all: raw Q/S -> bf16 fragments (+ rnq) ----------------------------
__global__ __launch_bounds__(256) void prep_all(const float* __restrict__ Q,
                                                const float* __restrict__ S,
                                                uint4* __restrict__ Qbf,
                                                uint4* __restrict__ Sbf,
                                                float* __restrict__ rnq) {
    const int blk = blockIdx.x;
    if (blk < 256) {
        const int b = blk >> 2;
        const int col = ((blk & 3) << 8) + threadIdx.x;      // q in 0..1023
        const float* p = Q + (size_t)b * 65536 + col;
        float v[64];
        #pragma unroll
        for (int d = 0; d < 64; ++d) v[d] = p[(size_t)d << 10];
        float ss = 0.f;
        #pragma unroll
        for (int d = 0; d < 64; ++d) ss += v[d] * v[d];
        rnq[(b << 10) + col] = 1.0f / fmaxf(sqrtf(ss), 1e-12f);
        uint4* ob = Qbf + ((size_t)(b << 6) + (col >> 4)) * 128 + (col & 15);
        #pragma unroll
        for (int h = 0; h < 8; ++h)
            ob[h << 4] = pack8cvt(&v[h << 3]);
    } else {
        const int bw = (blk - 256) >> 2;
        const int col = ((blk & 3) << 8) + threadIdx.x;      // s in 0..1023
        const float* p = S + (size_t)bw * 65536 + col;
        float v[64];
        #pragma unroll
        for (int d = 0; d < 64; ++d) v[d] = p[(size_t)d << 10];
        float ss = 0.f;
        #pragma unroll
        for (int d = 0; d < 64; ++d) ss += v[d] * v[d];
        const float rs = 1.0f / fmaxf(sqrtf(ss), 1e-12f);
        #pragma unroll
        for (int d = 0; d < 64; ++d) v[d] *= rs;
        uint4* ob = Sbf + ((size_t)(bw << 6) + (col >> 4)) * 128 + (col & 15);
        #pragma unroll
        for (int h = 0; h < 8; ++h)
            ob[h << 4] = pack8cvt(&v[h << 3]);
    }
}

// one 16-s tile vs 4 q-tiles: 2 ds_read_b128, 8 MFMA, 48 INS-VALU (4 chains)
__device__ __forceinline__ void compute_tile4(const uint4* sp, int lane,
                                              const bf16x8 (&bq)[4][2],
                                              float (&t0)[4], float (&t1)[4],
                                              float (&t2)[4]) {
    bf16x8 a0 = *reinterpret_cast<const bf16x8*>(&sp[lane]);
    bf16x8 a1 = *reinterpret_cast<const bf16x8*>(&sp[64 + lane]);
    const f32x4 z = {0.f, 0.f, 0.f, 0.f};
    f32x4 c[4];
    __builtin_amdgcn_s_setprio(1);
    #pragma unroll
    for (int qt = 0; qt < 4; ++qt) {
        c[qt] = __builtin_amdgcn_mfma_f32_16x16x32_bf16(a0, bq[qt][0], z, 0, 0, 0);
        c[qt] = __builtin_amdgcn_mfma_f32_16x16x32_bf16(a1, bq[qt][1], c[qt], 0, 0, 0);
    }
    __builtin_amdgcn_s_setprio(0);
    #pragma unroll
    for (int qt = 0; qt < 4; ++qt) {
        INS(c[qt][0], t0[qt], t1[qt], t2[qt]);
        INS(c[qt][1], t0[qt], t1[qt], t2[qt]);
        INS(c[qt][2], t0[qt], t1[qt], t2[qt]);
        INS(c[qt][3], t0[qt], t1[qt], t2[qt]);
    }
}

// ---- main: barrier-free per-wave pipelines ----------------------------------
// grid 2560 (logical l: qc = l&7 -> 8 q-tiles, bw = l>>3), block 256 = 4 waves:
// g = wv>>1 (q-group of 4 tiles), h = wv&1 (s-half of 32 tiles).
// Each wave: private 5-slot x 2KB LDS ring, stage 3 tiles ahead, vmcnt(6).
__global__ __launch_bounds__(256, 4) void knn_main(const uint4* __restrict__ Qbf,
                                                   const uint4* __restrict__ Sbf,
                                                   const float* __restrict__ rnq,
                                                   float* __restrict__ partial) {
    __shared__ uint4 ring[4][5 * 128];   // 4 waves x 10KB = 40960 B
    const int lin = blockIdx.x;
    const int l   = (lin & 7) * 320 + (lin >> 3);   // 2560 = 8*320, bijective
    const int qc  = l & 7;
    const int bw  = l >> 3;                          // b*5 + w
    const int b   = bw / 5;
    const int wv = threadIdx.x >> 6, lane = threadIdx.x & 63;
    const int g  = wv >> 1, h = wv & 1;

    // Q fragments: q-tiles qc*8 + g*4 + {0..3}
    const uint4* qb = Qbf + ((size_t)(b << 6) + (qc << 3) + (g << 2)) * 128 + lane;
    bf16x8 bq[4][2];
    #pragma unroll
    for (int qt = 0; qt < 4; ++qt)
        #pragma unroll
        for (int c = 0; c < 2; ++c)
            bq[qt][c] = *reinterpret_cast<const bf16x8*>(&qb[qt * 128 + (c << 6)]);

    // wave's global s-range: tiles h*32 .. h*32+31 (byte offset h<<16)
    const char* sbyte = (const char*)(Sbf + (size_t)bw * 8192) + ((size_t)h << 16)
                        + (size_t)lane * 16;
    uint4* myring = &ring[wv][0];

    float t0[4], t1[4], t2[4];
    #pragma unroll
    for (int qt = 0; qt < 4; ++qt) { t0[qt] = -1e30f; t1[qt] = -1e30f; t2[qt] = -1e30f; }

    // prologue: stage tiles 0..2 into slots 0..2 (2 gloads per tile)
    #pragma unroll
    for (int t = 0; t < 3; ++t) {
        gload16(sbyte + (size_t)t * 2048,        &myring[t * 128]);
        gload16(sbyte + (size_t)t * 2048 + 1024, &myring[t * 128 + 64]);
    }

    // main loop: NO barriers; per-wave vmcnt pacing only
    int rslot = 0, wslot = 3;
    for (int t = 0; t <= 28; ++t) {
        gload16(sbyte + (size_t)(t + 3) * 2048,        &myring[wslot * 128]);
        gload16(sbyte + (size_t)(t + 3) * 2048 + 1024, &myring[wslot * 128 + 64]);
        asm volatile("s_waitcnt vmcnt(6)" ::: "memory");
        compute_tile4(&myring[rslot * 128], lane, bq, t0, t1, t2);
        if (++rslot == 5) rslot = 0;
        if (++wslot == 5) wslot = 0;
    }
    // tail: tiles 29,30,31 in slots 4,0,1
    asm volatile("s_waitcnt vmcnt(4)" ::: "memory");
    compute_tile4(&myring[4 * 128], lane, bq, t0, t1, t2);
    asm volatile("s_waitcnt vmcnt(2)" ::: "memory");
    compute_tile4(&myring[0], lane, bq, t0, t1, t2);
    asm volatile("s_waitcnt vmcnt(0)" ::: "memory");
    compute_tile4(&myring[1 * 128], lane, bq, t0, t1, t2);

    // merge top-3 across the 4 lane-groups sharing each q (within wave)
    #pragma unroll
    for (int qt = 0; qt < 4; ++qt) {
        #pragma unroll
        for (int m = 16; m <= 32; m <<= 1) {
            float b0 = __shfl_xor(t0[qt], m);
            float b1 = __shfl_xor(t1[qt], m);
            float b2 = __shfl_xor(t2[qt], m);
            INS(b0, t0[qt], t1[qt], t2[qt]);
            INS(b1, t0[qt], t1[qt], t2[qt]);
            INS(b2, t0[qt], t1[qt], t2[qt]);
        }
    }

    // cross-s-half merge: h=1 wave publishes triples into ITS OWN ring region
    if (h == 1) {
        float* tb = (float*)&ring[wv][0];
        if (lane < 16) {
            #pragma unroll
            for (int qt = 0; qt < 4; ++qt) {
                tb[qt * 48 + lane]      = t0[qt];
                tb[qt * 48 + 16 + lane] = t1[qt];
                tb[qt * 48 + 32 + lane] = t2[qt];
            }
        }
    }
    __syncthreads();
    if (h == 0) {
        const float* tb = (const float*)&ring[wv + 1][0];
        float s3 = 0.f;
        #pragma unroll
        for (int qt = 0; qt < 4; ++qt) {
            float u0 = tb[qt * 48 + (lane & 15)];
            float u1 = tb[qt * 48 + 16 + (lane & 15)];
            float u2 = tb[qt * 48 + 32 + (lane & 15)];
            INS(u0, t0[qt], t1[qt], t2[qt]);
            INS(u1, t0[qt], t1[qt], t2[qt]);
            INS(u2, t0[qt], t1[qt], t2[qt]);
            const int qg = (qc << 7) + (g << 6) + (qt << 4) + (lane & 15);
            s3 += (t0[qt] + t1[qt] + t2[qt]) * rnq[(b << 10) + qg];
        }
        #pragma unroll
        for (int m = 1; m < 64; m <<= 1) s3 += __shfl_xor(s3, m);
        s3 *= 0.25f;                   // each q replicated over 4 lane-groups
        if (lane == 0) partial[(size_t)bw * 16 + qc * 2 + g] = s3;
    }
}

__global__ void finalize16(const float* __restrict__ partial, float* __restrict__ out) {
    int i = blockIdx.x * blockDim.x + threadIdx.x;
    if (i < 320) {
        float a = 0.f;
        #pragma unroll
        for (int k = 0; k < 16; ++k) a += partial[16 * i + k];
        out[i] = a;
    }
}

// ============================ fallback path (round-2) ========================
__global__ void norms_kernel(const float* __restrict__ Q, const float* __restrict__ S,
                             float* __restrict__ rnq, float* __restrict__ rns) {
    int gid = blockIdx.x * blockDim.x + threadIdx.x;
    if (gid < 65536) {
        int b = gid >> 10, qi = gid & 1023;
        const float* p = Q + (size_t)b * 65536 + qi;
        float ss = 0.f;
        #pragma unroll
        for (int d = 0; d < 64; ++d) { float v = p[(size_t)d * 1024]; ss += v * v; }
        rnq[gid] = 1.0f / fmaxf(sqrtf(ss), 1e-12f);
    } else {
        int v = gid - 65536;
        int bw = v >> 10, si = v & 1023;
        const float* p = S + (size_t)bw * 65536 + si;
        float ss = 0.f;
        #pragma unroll
        for (int d = 0; d < 64; ++d) { float x = p[(size_t)d * 1024]; ss += x * x; }
        rns[v] = 1.0f / fmaxf(sqrtf(ss), 1e-12f);
    }
}

__global__ __launch_bounds__(512, 4) void knn_fb(
        const float* __restrict__ Q, const float* __restrict__ S,
        const float* __restrict__ rnq, const float* __restrict__ rns,
        float* __restrict__ partial) {
    __shared__ uint4 qfrag[16 * 128];
    __shared__ uint4 sfrag[2][4 * 128];
    __shared__ float wsum[8];

    const int qc = blockIdx.x, w = blockIdx.y, b = blockIdx.z;
    const int t = threadIdx.x, wv = t >> 6, lane = t & 63;

    const float* Qb   = Q + (size_t)b * 65536;
    const float* Sb   = S + (size_t)(b * 5 + w) * 65536;
    const float* rnqb = rnq + (b << 10);
    const float* rnsb = rns + ((b * 5 + w) << 10);

    bf16x8 bq[4][2];
    for (int ph = 0; ph < 2; ++ph) {
        for (int sub = 0; sub < 4; ++sub) {
            int qg = (qc << 9) + (ph << 8) + (sub << 6) + lane;
            float v[8];
            #pragma unroll
            for (int i = 0; i < 8; ++i)
                v[i] = Qb[(size_t)((wv << 3) + i) * 1024 + qg];
            qfrag[((sub << 2) + (lane >> 4)) * 128 + (wv << 4) + (lane & 15)] = pack8cvt(v);
        }
        __syncthreads();
        if ((wv >> 2) == ph) {
            #pragma unroll
            for (int qt = 0; qt < 4; ++qt)
                #pragma unroll
                for (int c = 0; c < 2; ++c)
                    bq[qt][c] = *reinterpret_cast<const bf16x8*>(
                        &qfrag[(((wv & 3) << 2) + qt) * 128 + (c << 6) + lane]);
        }
        __syncthreads();
    }

    {
        float sv[8]; float rs = rnsb[lane];
        #pragma unroll
        for (int i = 0; i < 8; ++i)
            sv[i] = Sb[(size_t)((wv << 3) + i) * 1024 + lane] * rs;
        sfrag[0][(lane >> 4) * 128 + (wv << 4) + (lane & 15)] = pack8cvt(sv);
    }
    __syncthreads();

    float t0[4], t1[4], t2[4];
    #pragma unroll
    for (int qt = 0; qt < 4; ++qt) { t0[qt] = -1e30f; t1[qt] = -1e30f; t2[qt] = -1e30f; }
    int cur = 0;
    const float* sp = Sb + ((wv << 3) << 10) + lane;

    for (int blk = 0; blk < 16; ++blk) {
        float sv[8]; float rs;
        if (blk < 15) {
            const int sb_ = (blk + 1) << 6;
            rs = rnsb[sb_ + lane];
            #pragma unroll
            for (int i = 0; i < 8; ++i)
                sv[i] = sp[(size_t)(i << 10) + sb_];
        }
        #pragma unroll
        for (int st = 0; st < 4; ++st) {
            bf16x8 a0 = *reinterpret_cast<const bf16x8*>(&sfrag[cur][st * 128 + lane]);
            bf16x8 a1 = *reinterpret_cast<const bf16x8*>(&sfrag[cur][st * 128 + 64 + lane]);
            #pragma unroll
            for (int qt = 0; qt < 4; ++qt) {
                f32x4 c = {0.f, 0.f, 0.f, 0.f};
                c = __builtin_amdgcn_mfma_f32_16x16x32_bf16(a0, bq[qt][0], c, 0, 0, 0);
                c = __builtin_amdgcn_mfma_f32_16x16x32_bf16(a1, bq[qt][1], c, 0, 0, 0);
                #pragma unroll
                for (int j = 0; j < 4; ++j)
                    INS(c[j], t0[qt], t1[qt], t2[qt]);
            }
        }
        if (blk < 15) {
            #pragma unroll
            for (int i = 0; i < 8; ++i) sv[i] *= rs;
            sfrag[cur ^ 1][(lane >> 4) * 128 + (wv << 4) + (lane & 15)] = pack8cvt(sv);
        }
        __syncthreads();
        cur ^= 1;
    }

    float s3 = 0.f;
    #pragma unroll
    for (int qt = 0; qt < 4; ++qt) {
        #pragma unroll
        for (int m = 16; m <= 32; m <<= 1) {
            float b0 = __shfl_xor(t0[qt], m);
            float b1 = __shfl_xor(t1[qt], m);
            float b2 = __shfl_xor(t2[qt], m);
            INS(b0, t0[qt], t1[qt], t2[qt]);
            INS(b1, t0[qt], t1[qt], t2[qt]);
            INS(b2, t0[qt], t1[qt], t2[qt]);
        }
        int qg = (qc << 9) + (wv << 6) + (qt << 4) + (lane & 15);
        s3 += (t0[qt] + t1[qt] + t2[qt]) * rnqb[qg];
    }
    #pragma unroll
    for (int m = 1; m < 64; m <<= 1) s3 += __shfl_xor(s3, m);
    s3 *= 0.25f;
    if (lane == 0) wsum[wv] = s3;
    __syncthreads();
    if (t == 0) {
        float acc = 0.f;
        #pragma unroll
        for (int i = 0; i < 8; ++i) acc += wsum[i];
        partial[((b * 5 + w) << 1) + qc] = acc;
    }
}

__global__ void finalize2(const float* __restrict__ partial, float* __restrict__ out) {
    int i = blockIdx.x * blockDim.x + threadIdx.x;
    if (i < 320)
        out[i] = partial[2 * i] + partial[2 * i + 1];
}

// =============================================================================
extern "C" void kernel_launch(void* const* d_in, const int* in_sizes, int n_in,
                              void* d_out, int out_size, void* d_ws, size_t ws_size,
                              hipStream_t stream) {
    const float* Q = (const float*)d_in[0];   // (64,64,32,32)
    const float* S = (const float*)d_in[1];   // (64,5,64,1024)
    float* out = (float*)d_out;               // (64,5)

    // fast-path ws: Qbf 8 MB | Sbf 41.9 MB | rnq 256 KB | partial 20 KB
    const size_t QBF = 8388608ull, SBF = 41943040ull, RNQ = 262144ull;
    const size_t NEED = QBF + SBF + RNQ + 20480ull;
    if (ws_size >= NEED) {
        char* base = (char*)d_ws;
        uint4* Qbf     = (uint4*)base;
        uint4* Sbf     = (uint4*)(base + QBF);
        float* rnq     = (float*)(base + QBF + SBF);
        float* partial = (float*)(base + QBF + SBF + RNQ);
        prep_all<<<1536, 256, 0, stream>>>(Q, S, Qbf, Sbf, rnq);
        knn_main<<<2560, 256, 0, stream>>>(Qbf, Sbf, rnq, partial);
        finalize16<<<2, 256, 0, stream>>>(partial, out);
    } else {
        float* rnq = (float*)d_ws;
        float* rns = rnq + 65536;
        float* partial = rns + 327680;
        norms_kernel<<<(65536 + 327680) / 256, 256, 0, stream>>>(Q, S, rnq, rns);
        knn_fb<<<dim3(2, 5, 64), 512, 0, stream>>>(Q, S, rnq, rns, partial);
        finalize2<<<2, 256, 0, stream>>>(partial, out);
    }
}

// Round 15
// 95.098 us; speedup vs baseline: 2.8909x; 1.0034x over previous
//
#include <hip/hip_runtime.h>
#include <hip/hip_bf16.h>

// LocalKNN: B=64, Way=5, D=64, Nq=1024, Ns=1024, K=3.
// out[b,w] = sum_q rnq[q] * sum(top3_s( <q_bq, shat_bws> ))
// Round 15: r14 barrier-free skeleton + DUAL top-3 sets per qt (8 chains;
// consecutive tiles' INS streams independent -> breaks the 384-step cross-tile
// dependent chain) + fully-static 5-slot schedule (compiler can pipeline
// tile t+1's ds_read/MFMA into tile t's INS shadow) + no setprio.

using bf16x8 = __attribute__((ext_vector_type(8))) short;  // 8 bf16 = 4 VGPRs
using f32x4  = __attribute__((ext_vector_type(4))) float;

__device__ inline unsigned cvt_pk_bf16(float lo, float hi) {
    unsigned r;
    asm("v_cvt_pk_bf16_f32 %0, %1, %2" : "=v"(r) : "v"(lo), "v"(hi));
    return r;
}

__device__ inline uint4 pack8cvt(const float* v) {
    uint4 r;
    r.x = cvt_pk_bf16(v[0], v[1]);
    r.y = cvt_pk_bf16(v[2], v[3]);
    r.z = cvt_pk_bf16(v[4], v[5]);
    r.w = cvt_pk_bf16(v[6], v[7]);
    return r;
}

// branchless insert of v into sorted top-3 (t0>=t1>=t2): 1 max + 2 med3
#define INS(v, T0, T1, T2) do {                         \
    float _v = (v);                                     \
    float _n0 = fmaxf((T0), _v);                        \
    float _n1 = __builtin_amdgcn_fmed3f(_v, (T0), (T1));\
    float _n2 = __builtin_amdgcn_fmed3f(_v, (T1), (T2));\
    (T0) = _n0; (T1) = _n1; (T2) = _n2;                 \
} while (0)

// async 16B/lane global->LDS (LDS dest = wave-uniform base + lane*16)
__device__ inline void gload16(const void* g, void* lds) {
    __builtin_amdgcn_global_load_lds(
        (const __attribute__((address_space(1))) unsigned int*)g,
        (__attribute__((address_space(3))) unsigned int*)lds,
        16, 0, 0);
}

// ============================= fast path =====================================
// Fragment layout: per 16-col tile, 128 uint4 slots; slot h*16 + r holds
// column (tile*16+r)'s elements d = 8h..8h+7 as 4 packed bf16-pairs.

// ---- prep_all: raw Q/S -> bf16 fragments (+ rnq) ----------------------------
__global__ __launch_bounds__(256) void prep_all(const float* __restrict__ Q,
                                                const float* __restrict__ S,
                                                uint4* __restrict__ Qbf,
                                                uint4* __restrict__ Sbf,
                                                float* __restrict__ rnq) {
    const int blk = blockIdx.x;
    if (blk < 256) {
        const int b = blk >> 2;
        const int col = ((blk & 3) << 8) + threadIdx.x;      // q in 0..1023
        const float* p = Q + (size_t)b * 65536 + col;
        float v[64];
        #pragma unroll
        for (int d = 0; d < 64; ++d) v[d] = p[(size_t)d << 10];
        float ss = 0.f;
        #pragma unroll
        for (int d = 0; d < 64; ++d) ss += v[d] * v[d];
        rnq[(b << 10) + col] = 1.0f / fmaxf(sqrtf(ss), 1e-12f);
        uint4* ob = Qbf + ((size_t)(b << 6) + (col >> 4)) * 128 + (col & 15);
        #pragma unroll
        for (int h = 0; h < 8; ++h)
            ob[h << 4] = pack8cvt(&v[h << 3]);
    } else {
        const int bw = (blk - 256) >> 2;
        const int col = ((blk & 3) << 8) + threadIdx.x;      // s in 0..1023
        const float* p = S + (size_t)bw * 65536 + col;
        float v[64];
        #pragma unroll
        for (int d = 0; d < 64; ++d) v[d] = p[(size_t)d << 10];
        float ss = 0.f;
        #pragma unroll
        for (int d = 0; d < 64; ++d) ss += v[d] * v[d];
        const float rs = 1.0f / fmaxf(sqrtf(ss), 1e-12f);
        #pragma unroll
        for (int d = 0; d < 64; ++d) v[d] *= rs;
        uint4* ob = Sbf + ((size_t)(bw << 6) + (col >> 4)) * 128 + (col & 15);
        #pragma unroll
        for (int h = 0; h < 8; ++h)
            ob[h << 4] = pack8cvt(&v[h << 3]);
    }
}

// one 16-s tile vs 4 q-tiles: 2 ds_read_b128, 8 MFMA, 48 INS into given t-set
__device__ __forceinline__ void compute_tile4(const uint4* sp, int lane,
                                              const bf16x8 (&bq)[4][2],
                                              float (&t0)[4], float (&t1)[4],
                                              float (&t2)[4]) {
    bf16x8 a0 = *reinterpret_cast<const bf16x8*>(&sp[lane]);
    bf16x8 a1 = *reinterpret_cast<const bf16x8*>(&sp[64 + lane]);
    const f32x4 z = {0.f, 0.f, 0.f, 0.f};
    f32x4 c[4];
    #pragma unroll
    for (int qt = 0; qt < 4; ++qt) {
        c[qt] = __builtin_amdgcn_mfma_f32_16x16x32_bf16(a0, bq[qt][0], z, 0, 0, 0);
        c[qt] = __builtin_amdgcn_mfma_f32_16x16x32_bf16(a1, bq[qt][1], c[qt], 0, 0, 0);
    }
    #pragma unroll
    for (int qt = 0; qt < 4; ++qt) {
        INS(c[qt][0], t0[qt], t1[qt], t2[qt]);
        INS(c[qt][1], t0[qt], t1[qt], t2[qt]);
        INS(c[qt][2], t0[qt], t1[qt], t2[qt]);
        INS(c[qt][3], t0[qt], t1[qt], t2[qt]);
    }
}

// ---- main: barrier-free per-wave pipelines, dual t-sets ---------------------
// grid 2560 (logical l: qc = l&7, bw = l>>3), block 256 = 4 waves:
// g = wv>>1 (q-group of 4 tiles), h = wv&1 (s-half of 32 tiles).
// Each wave: private 5-slot x 2KB LDS ring, stage 3 tiles ahead, vmcnt(6).
__global__ __launch_bounds__(256, 4) void knn_main(const uint4* __restrict__ Qbf,
                                                   const uint4* __restrict__ Sbf,
                                                   const float* __restrict__ rnq,
                                                   float* __restrict__ partial) {
    __shared__ uint4 ring[4][5 * 128];   // 4 waves x 10KB = 40960 B
    const int lin = blockIdx.x;
    const int l   = (lin & 7) * 320 + (lin >> 3);   // 2560 = 8*320, bijective
    const int qc  = l & 7;
    const int bw  = l >> 3;                          // b*5 + w
    const int b   = bw / 5;
    const int wv = threadIdx.x >> 6, lane = threadIdx.x & 63;
    const int g  = wv >> 1, h = wv & 1;

    // Q fragments: q-tiles qc*8 + g*4 + {0..3}
    const uint4* qb = Qbf + ((size_t)(b << 6) + (qc << 3) + (g << 2)) * 128 + lane;
    bf16x8 bq[4][2];
    #pragma unroll
    for (int qt = 0; qt < 4; ++qt)
        #pragma unroll
        for (int c = 0; c < 2; ++c)
            bq[qt][c] = *reinterpret_cast<const bf16x8*>(&qb[qt * 128 + (c << 6)]);

    // wave's global s-range: tiles h*32 .. h*32+31 (byte offset h<<16)
    const char* sbyte = (const char*)(Sbf + (size_t)bw * 8192) + ((size_t)h << 16)
                        + (size_t)lane * 16;
    uint4* myring = &ring[wv][0];

    // dual top-3 sets per qt: A (even phase), B (odd phase) -> 8 indep chains
    float tA0[4], tA1[4], tA2[4], tB0[4], tB1[4], tB2[4];
    #pragma unroll
    for (int qt = 0; qt < 4; ++qt) {
        tA0[qt] = -1e30f; tA1[qt] = -1e30f; tA2[qt] = -1e30f;
        tB0[qt] = -1e30f; tB1[qt] = -1e30f; tB2[qt] = -1e30f;
    }

    // prologue: stage tiles 0..2 into slots 0..2
    #pragma unroll
    for (int t = 0; t < 3; ++t) {
        gload16(sbyte + (size_t)t * 2048,        &myring[t * 128]);
        gload16(sbyte + (size_t)t * 2048 + 1024, &myring[t * 128 + 64]);
    }

    // main: tiles 0..24 in 5 unrolled quintets, static slots, no barriers
    #pragma unroll 1
    for (int base = 0; base < 25; base += 5) {
        #pragma unroll
        for (int u = 0; u < 5; ++u) {
            const int tt = base + u;
            const int ws = (u + 3 >= 5) ? (u - 2) : (u + 3);   // static
            gload16(sbyte + (size_t)(tt + 3) * 2048,        &myring[ws * 128]);
            gload16(sbyte + (size_t)(tt + 3) * 2048 + 1024, &myring[ws * 128 + 64]);
            asm volatile("s_waitcnt vmcnt(6)" ::: "memory");
            if ((u & 1) == 0)
                compute_tile4(&myring[u * 128], lane, bq, tA0, tA1, tA2);
            else
                compute_tile4(&myring[u * 128], lane, bq, tB0, tB1, tB2);
        }
    }
    // epilogue: tiles 25..31 (stage 28..31, then drain), static slots
    gload16(sbyte + 28 * 2048,        &myring[3 * 128]);
    gload16(sbyte + 28 * 2048 + 1024, &myring[3 * 128 + 64]);
    asm volatile("s_waitcnt vmcnt(6)" ::: "memory");
    compute_tile4(&myring[0 * 128], lane, bq, tB0, tB1, tB2);   // tile 25
    gload16(sbyte + 29 * 2048,        &myring[4 * 128]);
    gload16(sbyte + 29 * 2048 + 1024, &myring[4 * 128 + 64]);
    asm volatile("s_waitcnt vmcnt(6)" ::: "memory");
    compute_tile4(&myring[1 * 128], lane, bq, tA0, tA1, tA2);   // tile 26
    gload16(sbyte + 30 * 2048,        &myring[0 * 128]);
    gload16(sbyte + 30 * 2048 + 1024, &myring[0 * 128 + 64]);
    asm volatile("s_waitcnt vmcnt(6)" ::: "memory");
    compute_tile4(&myring[2 * 128], lane, bq, tB0, tB1, tB2);   // tile 27
    gload16(sbyte + 31 * 2048,        &myring[1 * 128]);
    gload16(sbyte + 31 * 2048 + 1024, &myring[1 * 128 + 64]);
    asm volatile("s_waitcnt vmcnt(6)" ::: "memory");
    compute_tile4(&myring[3 * 128], lane, bq, tA0, tA1, tA2);   // tile 28
    asm volatile("s_waitcnt vmcnt(4)" ::: "memory");
    compute_tile4(&myring[4 * 128], lane, bq, tB0, tB1, tB2);   // tile 29
    asm volatile("s_waitcnt vmcnt(2)" ::: "memory");
    compute_tile4(&myring[0 * 128], lane, bq, tA0, tA1, tA2);   // tile 30
    asm volatile("s_waitcnt vmcnt(0)" ::: "memory");
    compute_tile4(&myring[1 * 128], lane, bq, tB0, tB1, tB2);   // tile 31

    // merge B into A, then across the 4 lane-groups sharing each q
    #pragma unroll
    for (int qt = 0; qt < 4; ++qt) {
        INS(tB0[qt], tA0[qt], tA1[qt], tA2[qt]);
        INS(tB1[qt], tA0[qt], tA1[qt], tA2[qt]);
        INS(tB2[qt], tA0[qt], tA1[qt], tA2[qt]);
        #pragma unroll
        for (int m = 16; m <= 32; m <<= 1) {
            float b0 = __shfl_xor(tA0[qt], m);
            float b1 = __shfl_xor(tA1[qt], m);
            float b2 = __shfl_xor(tA2[qt], m);
            INS(b0, tA0[qt], tA1[qt], tA2[qt]);
            INS(b1, tA0[qt], tA1[qt], tA2[qt]);
            INS(b2, tA0[qt], tA1[qt], tA2[qt]);
        }
    }

    // cross-s-half merge: h=1 wave publishes triples into ITS OWN ring region
    if (h == 1) {
        float* tb = (float*)&ring[wv][0];
        if (lane < 16) {
            #pragma unroll
            for (int qt = 0; qt < 4; ++qt) {
                tb[qt * 48 + lane]      = tA0[qt];
                tb[qt * 48 + 16 + lane] = tA1[qt];
                tb[qt * 48 + 32 + lane] = tA2[qt];
            }
        }
    }
    __syncthreads();
    if (h == 0) {
        const float* tb = (const float*)&ring[wv + 1][0];
        float s3 = 0.f;
        #pragma unroll
        for (int qt = 0; qt < 4; ++qt) {
            float u0 = tb[qt * 48 + (lane & 15)];
            float u1 = tb[qt * 48 + 16 + (lane & 15)];
            float u2 = tb[qt * 48 + 32 + (lane & 15)];
            INS(u0, tA0[qt], tA1[qt], tA2[qt]);
            INS(u1, tA0[qt], tA1[qt], tA2[qt]);
            INS(u2, tA0[qt], tA1[qt], tA2[qt]);
            const int qg = (qc << 7) + (g << 6) + (qt << 4) + (lane & 15);
            s3 += (tA0[qt] + tA1[qt] + tA2[qt]) * rnq[(b << 10) + qg];
        }
        #pragma unroll
        for (int m = 1; m < 64; m <<= 1) s3 += __shfl_xor(s3, m);
        s3 *= 0.25f;                   // each q replicated over 4 lane-groups
        if (lane == 0) partial[(size_t)bw * 16 + qc * 2 + g] = s3;
    }
}

__global__ void finalize16(const float* __restrict__ partial, float* __restrict__ out) {
    int i = blockIdx.x * blockDim.x + threadIdx.x;
    if (i < 320) {
        float a = 0.f;
        #pragma unroll
        for (int k = 0; k < 16; ++k) a += partial[16 * i + k];
        out[i] = a;
    }
}

// ============================ fallback path (round-2) ========================
__global__ void norms_kernel(const float* __restrict__ Q, const float* __restrict__ S,
                             float* __restrict__ rnq, float* __restrict__ rns) {
    int gid = blockIdx.x * blockDim.x + threadIdx.x;
    if (gid < 65536) {
        int b = gid >> 10, qi = gid & 1023;
        const float* p = Q + (size_t)b * 65536 + qi;
        float ss = 0.f;
        #pragma unroll
        for (int d = 0; d < 64; ++d) { float v = p[(size_t)d * 1024]; ss += v * v; }
        rnq[gid] = 1.0f / fmaxf(sqrtf(ss), 1e-12f);
    } else {
        int v = gid - 65536;
        int bw = v >> 10, si = v & 1023;
        const float* p = S + (size_t)bw * 65536 + si;
        float ss = 0.f;
        #pragma unroll
        for (int d = 0; d < 64; ++d) { float x = p[(size_t)d * 1024]; ss += x * x; }
        rns[v] = 1.0f / fmaxf(sqrtf(ss), 1e-12f);
    }
}

__global__ __launch_bounds__(512, 4) void knn_fb(
        const float* __restrict__ Q, const float* __restrict__ S,
        const float* __restrict__ rnq, const float* __restrict__ rns,
        float* __restrict__ partial) {
    __shared__ uint4 qfrag[16 * 128];
    __shared__ uint4 sfrag[2][4 * 128];
    __shared__ float wsum[8];

    const int qc = blockIdx.x, w = blockIdx.y, b = blockIdx.z;
    const int t = threadIdx.x, wv = t >> 6, lane = t & 63;

    const float* Qb   = Q + (size_t)b * 65536;
    const float* Sb   = S + (size_t)(b * 5 + w) * 65536;
    const float* rnqb = rnq + (b << 10);
    const float* rnsb = rns + ((b * 5 + w) << 10);

    bf16x8 bq[4][2];
    for (int ph = 0; ph < 2; ++ph) {
        for (int sub = 0; sub < 4; ++sub) {
            int qg = (qc << 9) + (ph << 8) + (sub << 6) + lane;
            float v[8];
            #pragma unroll
            for (int i = 0; i < 8; ++i)
                v[i] = Qb[(size_t)((wv << 3) + i) * 1024 + qg];
            qfrag[((sub << 2) + (lane >> 4)) * 128 + (wv << 4) + (lane & 15)] = pack8cvt(v);
        }
        __syncthreads();
        if ((wv >> 2) == ph) {
            #pragma unroll
            for (int qt = 0; qt < 4; ++qt)
                #pragma unroll
                for (int c = 0; c < 2; ++c)
                    bq[qt][c] = *reinterpret_cast<const bf16x8*>(
                        &qfrag[(((wv & 3) << 2) + qt) * 128 + (c << 6) + lane]);
        }
        __syncthreads();
    }

    {
        float sv[8]; float rs = rnsb[lane];
        #pragma unroll
        for (int i = 0; i < 8; ++i)
            sv[i] = Sb[(size_t)((wv << 3) + i) * 1024 + lane] * rs;
        sfrag[0][(lane >> 4) * 128 + (wv << 4) + (lane & 15)] = pack8cvt(sv);
    }
    __syncthreads();

    float t0[4], t1[4], t2[4];
    #pragma unroll
    for (int qt = 0; qt < 4; ++qt) { t0[qt] = -1e30f; t1[qt] = -1e30f; t2[qt] = -1e30f; }
    int cur = 0;
    const float* sp = Sb + ((wv << 3) << 10) + lane;

    for (int blk = 0; blk < 16; ++blk) {
        float sv[8]; float rs;
        if (blk < 15) {
            const int sb_ = (blk + 1) << 6;
            rs = rnsb[sb_ + lane];
            #pragma unroll
            for (int i = 0; i < 8; ++i)
                sv[i] = sp[(size_t)(i << 10) + sb_];
        }
        #pragma unroll
        for (int st = 0; st < 4; ++st) {
            bf16x8 a0 = *reinterpret_cast<const bf16x8*>(&sfrag[cur][st * 128 + lane]);
            bf16x8 a1 = *reinterpret_cast<const bf16x8*>(&sfrag[cur][st * 128 + 64 + lane]);
            #pragma unroll
            for (int qt = 0; qt < 4; ++qt) {
                f32x4 c = {0.f, 0.f, 0.f, 0.f};
                c = __builtin_amdgcn_mfma_f32_16x16x32_bf16(a0, bq[qt][0], c, 0, 0, 0);
                c = __builtin_amdgcn_mfma_f32_16x16x32_bf16(a1, bq[qt][1], c, 0, 0, 0);
                #pragma unroll
                for (int j = 0; j < 4; ++j)
                    INS(c[j], t0[qt], t1[qt], t2[qt]);
            }
        }
        if (blk < 15) {
            #pragma unroll
            for (int i = 0; i < 8; ++i) sv[i] *= rs;
            sfrag[cur ^ 1][(lane >> 4) * 128 + (wv << 4) + (lane & 15)] = pack8cvt(sv);
        }
        __syncthreads();
        cur ^= 1;
    }

    float s3 = 0.f;
    #pragma unroll
    for (int qt = 0; qt < 4; ++qt) {
        #pragma unroll
        for (int m = 16; m <= 32; m <<= 1) {
            float b0 = __shfl_xor(t0[qt], m);
            float b1 = __shfl_xor(t1[qt], m);
            float b2 = __shfl_xor(t2[qt], m);
            INS(b0, t0[qt], t1[qt], t2[qt]);
            INS(b1, t0[qt], t1[qt], t2[qt]);
            INS(b2, t0[qt], t1[qt], t2[qt]);
        }
        int qg = (qc << 9) + (wv << 6) + (qt << 4) + (lane & 15);
        s3 += (t0[qt] + t1[qt] + t2[qt]) * rnqb[qg];
    }
    #pragma unroll
    for (int m = 1; m < 64; m <<= 1) s3 += __shfl_xor(s3, m);
    s3 *= 0.25f;
    if (lane == 0) wsum[wv] = s3;
    __syncthreads();
    if (t == 0) {
        float acc = 0.f;
        #pragma unroll
        for (int i = 0; i < 8; ++i) acc += wsum[i];
        partial[((b * 5 + w) << 1) + qc] = acc;
    }
}

__global__ void finalize2(const float* __restrict__ partial, float* __restrict__ out) {
    int i = blockIdx.x * blockDim.x + threadIdx.x;
    if (i < 320)
        out[i] = partial[2 * i] + partial[2 * i + 1];
}

// =============================================================================
extern "C" void kernel_launch(void* const* d_in, const int* in_sizes, int n_in,
                              void* d_out, int out_size, void* d_ws, size_t ws_size,
                              hipStream_t stream) {
    const float* Q = (const float*)d_in[0];   // (64,64,32,32)
    const float* S = (const float*)d_in[1];   // (64,5,64,1024)
    float* out = (float*)d_out;               // (64,5)

    // fast-path ws: Qbf 8 MB | Sbf 41.9 MB | rnq 256 KB | partial 20 KB
    const size_t QBF = 8388608ull, SBF = 41943040ull, RNQ = 262144ull;
    const size_t NEED = QBF + SBF + RNQ + 20480ull;
    if (ws_size >= NEED) {
        char* base = (char*)d_ws;
        uint4* Qbf     = (uint4*)base;
        uint4* Sbf     = (uint4*)(base + QBF);
        float* rnq     = (float*)(base + QBF + SBF);
        float* partial = (float*)(base + QBF + SBF + RNQ);
        prep_all<<<1536, 256, 0, stream>>>(Q, S, Qbf, Sbf, rnq);
        knn_main<<<2560, 256, 0, stream>>>(Qbf, Sbf, rnq, partial);
        finalize16<<<2, 256, 0, stream>>>(partial, out);
    } else {
        float* rnq = (float*)d_ws;
        float* rns = rnq + 65536;
        float* partial = rns + 327680;
        norms_kernel<<<(65536 + 327680) / 256, 256, 0, stream>>>(Q, S, rnq, rns);
        knn_fb<<<dim3(2, 5, 64), 512, 0, stream>>>(Q, S, rnq, rns, partial);
        finalize2<<<2, 256, 0, stream>>>(partial, out);
    }
}